// Round 11
// baseline (4829.958 us; speedup 1.0000x reference)
//
#include <hip/hip_runtime.h>
#include <hip/hip_bf16.h>
#include <cstdint>
#include <cstddef>

// Problem constants (fixed by the reference)
#define BATCH 128
#define SEQ   512
#define DIM   1024
#define MROWS (BATCH * SEQ)          // 65536
#define NT    32                     // K sub-tiles of 32 (DIM/32)

typedef short short8 __attribute__((ext_vector_type(8)));
typedef __bf16 bf16x8 __attribute__((ext_vector_type(8)));
typedef float f32x4 __attribute__((ext_vector_type(4)));

// ---------- MFMA wrapper: accept either builtin signature (short8 or bf16x8) ----------
template <typename VA> struct other_frag { using type = bf16x8; };
template <> struct other_frag<bf16x8> { using type = short8; };

template <typename VA>
__device__ __forceinline__ auto try_mfma(VA a, VA b, f32x4 c, int)
    -> decltype(__builtin_amdgcn_mfma_f32_16x16x32_bf16(a, b, c, 0, 0, 0)) {
  return __builtin_amdgcn_mfma_f32_16x16x32_bf16(a, b, c, 0, 0, 0);
}
template <typename VA>
__device__ __forceinline__ f32x4 try_mfma(VA a, VA b, f32x4 c, long) {
  using O = typename other_frag<VA>::type;
  O a2 = __builtin_bit_cast(O, a);
  O b2 = __builtin_bit_cast(O, b);
  return __builtin_amdgcn_mfma_f32_16x16x32_bf16(a2, b2, c, 0, 0, 0);
}
__device__ __forceinline__ f32x4 mfma_bf16(short8 a, short8 b, f32x4 c) {
  return try_mfma(a, b, c, 0);
}

// ---------- helpers ----------
__device__ __forceinline__ unsigned short f32_to_bf16(float f) {
  union { float f; uint32_t u; } v; v.f = f;
  uint32_t u = v.u;
  u += 0x7FFFu + ((u >> 16) & 1u);   // round-to-nearest-even
  return (unsigned short)(u >> 16);
}

// 8 x f32 -> 8 x bf16 (RNE)
__device__ __forceinline__ short8 cvt8(f32x4 a, f32x4 b) {
  bf16x8 o;
  o[0] = (__bf16)a[0]; o[1] = (__bf16)a[1]; o[2] = (__bf16)a[2]; o[3] = (__bf16)a[3];
  o[4] = (__bf16)b[0]; o[5] = (__bf16)b[1]; o[6] = (__bf16)b[2]; o[7] = (__bf16)b[3];
  return __builtin_bit_cast(short8, o);
}

__device__ __forceinline__ void gload_lds16(const void* g, void* l) {
  __builtin_amdgcn_global_load_lds(
      (__attribute__((address_space(1))) void*)g,
      (__attribute__((address_space(3))) void*)l,
      16, 0, 0);
}

__device__ __forceinline__ float fast_tanh(float x) {
  x = fminf(fmaxf(x, -15.0f), 15.0f);
  float e = __expf(2.0f * x);
  return (e - 1.0f) / (e + 1.0f);
}

// ---------- kernel 1: W1 (D x D) -> W1t bf16 (transposed, [e][d]) ----------
__global__ __launch_bounds__(256) void w1t_kernel(const float* __restrict__ W1,
                                                  unsigned short* __restrict__ W1t) {
  __shared__ float tile[64][65];
  int bx = blockIdx.x & 15;    // e-tile
  int by = blockIdx.x >> 4;    // d-tile
  int t = threadIdx.x;
  int c = t & 63, r0 = t >> 6;
#pragma unroll
  for (int i = 0; i < 16; i++) {
    int r = i * 4 + r0;
    tile[r][c] = W1[(size_t)(by * 64 + r) * DIM + bx * 64 + c];
  }
  __syncthreads();
#pragma unroll
  for (int i = 0; i < 16; i++) {
    int r = i * 4 + r0;
    W1t[(size_t)(bx * 64 + r) * DIM + by * 64 + c] = f32_to_bf16(tile[c][r]);
  }
}

// ---------- kernel 2: 256x256-tile GEMM, A fp32 global->REG direct ----------
// C[m][e] = sum_d bf16(X[m][d]) * W1t[e][d]; scores[m] += sum_e tanh(C+b1[e])*w2[e]
//
// R10 post-mortem: conflicts 0 but LDS-read-bound (160 KB/CU/subtile).  Fix:
// A never touches LDS.  Each lane loads its OWN fragment data from global
// (frag mi: row = wr*128+mi*16+(lane&15), floats (lane>>4)*8 .. +8 = 2x
// global_load_dwordx4).  One instruction's 64 lanes cover 16 full 128-B row
// segments -> full cacheline use; XCD chunking keeps the A panel L2-resident
// across its 4 n-tile blocks.
//
// Depth-2 register pipeline, statically-named sets aE (even S) / aO (odd S)
// to keep all indexing compile-time (no scratch).  cvt to bf16 at consume.
// Per-wave VMEM invariant: 36 ops in flight (A 16 + B 2 per subtile, 2 deep);
// vmcnt(18) at iter top drains exactly {A(S), B(S)}; tails 18 -> 0.
// Raw s_barrier (NOT __syncthreads) so prefetches survive the barrier.
//
// B: unchanged measured-0 scheme. bf16 [256 rows][32 k], row-pairs in 128-B
// stored rows, chunk js = ((row&1)*4 + k16) ^ (srow&7); staged linearly via
// global_load_lds with source-side pre-swizzle; ring-3 x 16 KB = 48 KB LDS.
// B ring race-freedom: slot (S+2)%3 == (S-1)%3; all waves' reads of B(S-1)
// completed before they arrive at barrier(S); B(S+2) writes issue after
// barrier(S).
__global__ __launch_bounds__(512, 4) void gemm_score_kernel(
    const float* __restrict__ X,              // [MROWS][DIM] fp32
    const unsigned short* __restrict__ W1t,   // [DIM][DIM]  (e-major)
    const float* __restrict__ b1,
    const float* __restrict__ w2,
    float* __restrict__ scores) {             // [MROWS]
  __shared__ __align__(16) char lds[49152];   // B ring-3 only

  const int tid = threadIdx.x;
  const int lane = tid & 63;
  const int w = tid >> 6;                     // wave 0..7
  const int wr = w >> 2, wc = w & 3;          // 2 x 4 wave grid

  // chunked XCD swizzle: 1024 blocks, 8 XCDs, n-fastest within each chunk
  const int bx = blockIdx.x;
  const int swz = (bx & 7) * 128 + (bx >> 3);
  const int m0 = (swz >> 2) * 256;
  const int n0 = (swz & 3) * 256;

  // ---- A fragment base pointers (per-lane, fragment layout)
  const float* aPtr[8];
#pragma unroll
  for (int mi = 0; mi < 8; mi++)
    aPtr[mi] = X + (size_t)(m0 + wr * 128 + mi * 16 + (lane & 15)) * DIM
                 + (lane >> 4) * 8;

  // ---- B staging sources: 2 chunks/thread, sc = i*512 + tid (16B bf16 chunks)
  const unsigned short* bSrc[2];
#pragma unroll
  for (int i = 0; i < 2; i++) {
    int sc = i * 512 + tid;
    int srow = sc >> 3;
    int j = (sc & 7) ^ (srow & 7);
    int row = srow * 2 + (j >> 2);
    bSrc[i] = W1t + (size_t)(n0 + row) * DIM + (j & 3) * 8;
  }

  // ---- B fragment LDS byte offsets (within a 16KB buffer)
  int bOff[4];
#pragma unroll
  for (int ni = 0; ni < 4; ni++) {
    int row = wc * 64 + ni * 16 + (lane & 15);
    int srow = row >> 1;
    int ic = ((row & 1) * 4 + (lane >> 4)) ^ (srow & 7);
    bOff[ni] = srow * 128 + ic * 16;
  }

  f32x4 acc[8][4];
#pragma unroll
  for (int mi = 0; mi < 8; mi++)
#pragma unroll
    for (int ni = 0; ni < 4; ni++)
      acc[mi][ni] = (f32x4){0.f, 0.f, 0.f, 0.f};

  f32x4 aE[8][2], aO[8][2];                   // depth-2 A register sets
  short8 af[8], bfv[4];

#define LOAD_A(SET, S) do {                                             \
    _Pragma("unroll")                                                   \
    for (int mi = 0; mi < 8; mi++) {                                    \
      SET[mi][0] = *(const f32x4*)(aPtr[mi] + (S) * 32);                \
      SET[mi][1] = *(const f32x4*)(aPtr[mi] + (S) * 32 + 4);            \
    }                                                                   \
  } while (0)

#define STAGE_B(S) do {                                                 \
    const int bufB_ = ((S) % 3) * 16384;                                \
    const int koF_ = (S) * 32;                                          \
    gload_lds16(bSrc[0] + koF_, lds + bufB_ + w * 1024);                \
    gload_lds16(bSrc[1] + koF_, lds + bufB_ + 8192 + w * 1024);         \
  } while (0)

#define KITER(S, CURSET, PF, VMSTR) do {                                \
    asm volatile("s_waitcnt vmcnt(" VMSTR ")" ::: "memory");            \
    __builtin_amdgcn_s_barrier();                                       \
    __builtin_amdgcn_sched_barrier(0);                                  \
    _Pragma("unroll")                                                   \
    for (int mi = 0; mi < 8; mi++)                                      \
      af[mi] = cvt8(CURSET[mi][0], CURSET[mi][1]);                      \
    if (PF) {                                                           \
      LOAD_A(CURSET, (S) + 2);                                          \
      STAGE_B((S) + 2);                                                 \
    }                                                                   \
    __builtin_amdgcn_sched_barrier(0);                                  \
    const char* bufB_ = lds + ((S) % 3) * 16384;                        \
    _Pragma("unroll")                                                   \
    for (int ni = 0; ni < 4; ni++)                                      \
      bfv[ni] = *(const short8*)(bufB_ + bOff[ni]);                     \
    __builtin_amdgcn_s_setprio(1);                                      \
    _Pragma("unroll")                                                   \
    for (int mi = 0; mi < 8; mi++)                                      \
      _Pragma("unroll")                                                 \
      for (int ni = 0; ni < 4; ni++)                                    \
        acc[mi][ni] = mfma_bf16(af[mi], bfv[ni], acc[mi][ni]);          \
    __builtin_amdgcn_s_setprio(0);                                      \
  } while (0)

  // prologue: 2 sub-tiles in flight: A(0)->aE, B(0), A(1)->aO, B(1) = 36 ops
  LOAD_A(aE, 0);
  STAGE_B(0);
  LOAD_A(aO, 1);
  STAGE_B(1);

  for (int t = 0; t < 15; ++t) {
    const int S0 = 2 * t;
    KITER(S0, aE, 1, "18");
    KITER(S0 + 1, aO, 1, "18");
  }
  KITER(30, aE, 0, "18");
  KITER(31, aO, 0, "0");

#undef KITER
#undef STAGE_B
#undef LOAD_A

  // epilogue: scores[row] += sum over this wave's 64 cols of tanh(c + b1) * w2
  const int cg = lane >> 4;   // row group: rows cg*4 + j
  const int cl = lane & 15;   // col within fragment
#pragma unroll
  for (int mi = 0; mi < 8; mi++) {
    float p0 = 0.f, p1 = 0.f, p2 = 0.f, p3 = 0.f;
#pragma unroll
    for (int ni = 0; ni < 4; ni++) {
      int col = n0 + wc * 64 + ni * 16 + cl;
      float w2v = w2[col];
      float b1v = b1[col];
      p0 += fast_tanh(acc[mi][ni][0] + b1v) * w2v;
      p1 += fast_tanh(acc[mi][ni][1] + b1v) * w2v;
      p2 += fast_tanh(acc[mi][ni][2] + b1v) * w2v;
      p3 += fast_tanh(acc[mi][ni][3] + b1v) * w2v;
    }
#pragma unroll
    for (int off = 1; off < 16; off <<= 1) {
      p0 += __shfl_xor(p0, off);
      p1 += __shfl_xor(p1, off);
      p2 += __shfl_xor(p2, off);
      p3 += __shfl_xor(p3, off);
    }
    if (cl == 0) {
      int row = m0 + wr * 128 + mi * 16 + cg * 4;
      atomicAdd(&scores[row + 0], p0);
      atomicAdd(&scores[row + 1], p1);
      atomicAdd(&scores[row + 2], p2);
      atomicAdd(&scores[row + 3], p3);
    }
  }
}

// ---------- kernel 3: masked softmax + u_att + u_last (fp32 X) ----------
__global__ __launch_bounds__(256) void attn_uatt_kernel(
    const float* __restrict__ X,
    const float* __restrict__ scores,
    const int* __restrict__ mask,
    float* __restrict__ u_att,
    float* __restrict__ u_last) {
  const int b = blockIdx.x;
  const int half = blockIdx.y;            // d-range [half*512, half*512+512)
  const int tid = threadIdx.x;
  const int lane = tid & 63;
  const int wave = tid >> 6;

  __shared__ float attn[SEQ];
  __shared__ float rbuf[4];
  __shared__ float part[3][64 * 9];       // padded stride 9

  float s0 = scores[(size_t)b * SEQ + tid];
  float s1 = scores[(size_t)b * SEQ + 256 + tid];
  if (mask[(size_t)b * SEQ + tid]) s0 = -1000000000.0f;
  if (mask[(size_t)b * SEQ + 256 + tid]) s1 = -1000000000.0f;

  float mx = fmaxf(s0, s1);
#pragma unroll
  for (int off = 1; off < 64; off <<= 1) mx = fmaxf(mx, __shfl_xor(mx, off));
  if (lane == 0) rbuf[wave] = mx;
  __syncthreads();
  mx = fmaxf(fmaxf(rbuf[0], rbuf[1]), fmaxf(rbuf[2], rbuf[3]));

  float p0 = expf(s0 - mx), p1 = expf(s1 - mx);
  float sm = p0 + p1;
#pragma unroll
  for (int off = 1; off < 64; off <<= 1) sm += __shfl_xor(sm, off);
  __syncthreads();
  if (lane == 0) rbuf[wave] = sm;
  __syncthreads();
  sm = rbuf[0] + rbuf[1] + rbuf[2] + rbuf[3];
  float inv = 1.0f / sm;
  attn[tid] = p0 * inv;
  attn[tid + 256] = p1 * inv;
  __syncthreads();

  // u_last: exact fp32 copy of X[:, 511, :] (this block's 512-d half)
  if (tid < 128) {
    ((f32x4*)u_last)[(size_t)b * 256 + half * 128 + tid] =
        ((const f32x4*)X)[((size_t)b * SEQ + (SEQ - 1)) * 256 + half * 128 + tid];
  }

  // u_att[b][d] = sum_s attn[s] * X[b][s][d]; block covers 512 d (64 groups of 8)
  const int col = tid & 63;            // 8-float group within the half
  const int sh = tid >> 6;             // s-range split: [sh*128, sh*128+128)
  const f32x4* Xp = (const f32x4*)X + (size_t)b * SEQ * 256 + half * 128 + col * 2;
  f32x4 a0 = {0.f, 0.f, 0.f, 0.f}, a1 = {0.f, 0.f, 0.f, 0.f};
  for (int s = sh * 128; s < sh * 128 + 128; s++) {
    float wgt = attn[s];
    a0 += wgt * Xp[(size_t)s * 256];
    a1 += wgt * Xp[(size_t)s * 256 + 1];
  }
  if (sh) {
#pragma unroll
    for (int j = 0; j < 4; j++) part[sh - 1][col * 9 + j] = a0[j];
#pragma unroll
    for (int j = 0; j < 4; j++) part[sh - 1][col * 9 + 4 + j] = a1[j];
  }
  __syncthreads();
  if (sh == 0) {
#pragma unroll
    for (int j = 0; j < 4; j++)
      a0[j] += part[0][col * 9 + j] + part[1][col * 9 + j] + part[2][col * 9 + j];
#pragma unroll
    for (int j = 0; j < 4; j++)
      a1[j] += part[0][col * 9 + 4 + j] + part[1][col * 9 + 4 + j] + part[2][col * 9 + 4 + j];
    f32x4* dst = (f32x4*)(u_att + (size_t)b * DIM + half * 512 + col * 8);
    dst[0] = a0;
    dst[1] = a1;
  }
}

// ---------- launcher ----------
extern "C" void kernel_launch(void* const* d_in, const int* in_sizes, int n_in,
                              void* d_out, int out_size, void* d_ws, size_t ws_size,
                              hipStream_t stream) {
  const float* X    = (const float*)d_in[0];   // [128][512][1024] fp32
  const int*   mask = (const int*)d_in[1];     // [128][512] int32 (bool)
  const float* W1   = (const float*)d_in[2];   // [1024][1024]
  const float* b1   = (const float*)d_in[3];   // [1024]
  const float* w2   = (const float*)d_in[4];   // [1024]

  float* out    = (float*)d_out;
  float* u_last = out;                          // [128][1024]
  float* u_att  = out + BATCH * DIM;            // [128][1024]

  char* ws = (char*)d_ws;
  unsigned short* W1t = (unsigned short*)ws;                        // 2 MB
  float* scores = (float*)(ws + (size_t)DIM * DIM * 2);             // 256 KB

  hipMemsetAsync(scores, 0, MROWS * sizeof(float), stream);
  hipLaunchKernelGGL(w1t_kernel, dim3(256), dim3(256), 0, stream, W1, W1t);
  hipLaunchKernelGGL(gemm_score_kernel, dim3(1024), dim3(512), 0, stream,
                     X, W1t, b1, w2, scores);
  hipLaunchKernelGGL(attn_uatt_kernel, dim3(128, 2), dim3(256), 0, stream,
                     X, scores, mask, u_att, u_last);
}

// Round 12
// 695.388 us; speedup vs baseline: 6.9457x; 6.9457x over previous
//
#include <hip/hip_runtime.h>
#include <hip/hip_bf16.h>
#include <cstdint>
#include <cstddef>

// Problem constants (fixed by the reference)
#define BATCH 128
#define SEQ   512
#define DIM   1024
#define MROWS (BATCH * SEQ)          // 65536
#define NT    32                     // K sub-tiles of 32 (DIM/32)

typedef short short8 __attribute__((ext_vector_type(8)));
typedef __bf16 bf16x8 __attribute__((ext_vector_type(8)));
typedef float f32x4 __attribute__((ext_vector_type(4)));

// ---------- MFMA wrapper: accept either builtin signature (short8 or bf16x8) ----------
template <typename VA> struct other_frag { using type = bf16x8; };
template <> struct other_frag<bf16x8> { using type = short8; };

template <typename VA>
__device__ __forceinline__ auto try_mfma(VA a, VA b, f32x4 c, int)
    -> decltype(__builtin_amdgcn_mfma_f32_16x16x32_bf16(a, b, c, 0, 0, 0)) {
  return __builtin_amdgcn_mfma_f32_16x16x32_bf16(a, b, c, 0, 0, 0);
}
template <typename VA>
__device__ __forceinline__ f32x4 try_mfma(VA a, VA b, f32x4 c, long) {
  using O = typename other_frag<VA>::type;
  O a2 = __builtin_bit_cast(O, a);
  O b2 = __builtin_bit_cast(O, b);
  return __builtin_amdgcn_mfma_f32_16x16x32_bf16(a2, b2, c, 0, 0, 0);
}
__device__ __forceinline__ f32x4 mfma_bf16(short8 a, short8 b, f32x4 c) {
  return try_mfma(a, b, c, 0);
}

// ---------- helpers ----------
__device__ __forceinline__ unsigned short f32_to_bf16(float f) {
  union { float f; uint32_t u; } v; v.f = f;
  uint32_t u = v.u;
  u += 0x7FFFu + ((u >> 16) & 1u);   // round-to-nearest-even
  return (unsigned short)(u >> 16);
}

// 8 x f32 -> 8 x bf16 (RNE)
__device__ __forceinline__ short8 cvt8(f32x4 a, f32x4 b) {
  bf16x8 o;
  o[0] = (__bf16)a[0]; o[1] = (__bf16)a[1]; o[2] = (__bf16)a[2]; o[3] = (__bf16)a[3];
  o[4] = (__bf16)b[0]; o[5] = (__bf16)b[1]; o[6] = (__bf16)b[2]; o[7] = (__bf16)b[3];
  return __builtin_bit_cast(short8, o);
}

__device__ __forceinline__ void gload_lds16(const void* g, void* l) {
  __builtin_amdgcn_global_load_lds(
      (__attribute__((address_space(1))) void*)g,
      (__attribute__((address_space(3))) void*)l,
      16, 0, 0);
}

__device__ __forceinline__ float fast_tanh(float x) {
  x = fminf(fmaxf(x, -15.0f), 15.0f);
  float e = __expf(2.0f * x);
  return (e - 1.0f) / (e + 1.0f);
}

// ---------- kernel 1: W1 (D x D) -> W1t bf16 (transposed, [e][d]) ----------
__global__ __launch_bounds__(256) void w1t_kernel(const float* __restrict__ W1,
                                                  unsigned short* __restrict__ W1t) {
  __shared__ float tile[64][65];
  int bx = blockIdx.x & 15;    // e-tile
  int by = blockIdx.x >> 4;    // d-tile
  int t = threadIdx.x;
  int c = t & 63, r0 = t >> 6;
#pragma unroll
  for (int i = 0; i < 16; i++) {
    int r = i * 4 + r0;
    tile[r][c] = W1[(size_t)(by * 64 + r) * DIM + bx * 64 + c];
  }
  __syncthreads();
#pragma unroll
  for (int i = 0; i < 16; i++) {
    int r = i * 4 + r0;
    W1t[(size_t)(bx * 64 + r) * DIM + by * 64 + c] = f32_to_bf16(tile[c][r]);
  }
}

// ---------- kernel 2: 256x256-tile GEMM, A fp32 global->REG direct ----------
// C[m][e] = sum_d bf16(X[m][d]) * W1t[e][d]; scores[m] += sum_e tanh(C+b1[e])*w2[e]
//
// R11 structure with the spill-cause fixed: __launch_bounds__(512,2) (VGPR cap
// 256, R11's (512,4) capped at ~128 -> 10 GB scratch), and a SINGLE A register
// set (depth-1) so peak regs ~ acc 128 + aC 64 + af 32 + bfv 16 ~ 245 < 256.
//
// Per iter S: vmcnt(2) drains {B(S), A(S)} (B(S+1) stays in flight) ->
// barrier -> cvt aC -> af (frees aC via in-order WAR) -> issue A(S+1) (16
// global_load_dwordx4, per-lane fragment addresses) + B(S+2) (2 gload_lds,
// ring-3) -> bfv ds_reads -> 32 MFMA (setprio).  Issue order keeps the VMEM
// queue as [B(S+1), A(S+1), B(S+2)] so vmcnt(2) is exact each iter.
// Tail: iter 30 loads A(31) only; iter 31 waits vmcnt(0).
//
// A-latency cover: one full subtile (~1200 cyc block-level); the A panel slice
// (32 KB/subtile) is L1/L2-resident -- 4 wc-waves read identical addresses
// (L1), the 4 n-blocks of each m-panel are dispatch-adjacent on one XCD (L2).
//
// B: unchanged measured-0 scheme (bf16 row-pairs in 128-B stored rows, chunk
// js = ((row&1)*4 + k16) ^ (srow&7)); ring-3 x 16 KB = 48 KB LDS total.
__global__ __launch_bounds__(512, 2) void gemm_score_kernel(
    const float* __restrict__ X,              // [MROWS][DIM] fp32
    const unsigned short* __restrict__ W1t,   // [DIM][DIM]  (e-major)
    const float* __restrict__ b1,
    const float* __restrict__ w2,
    float* __restrict__ scores) {             // [MROWS]
  __shared__ __align__(16) char lds[49152];   // B ring-3 only

  const int tid = threadIdx.x;
  const int lane = tid & 63;
  const int w = tid >> 6;                     // wave 0..7
  const int wr = w >> 2, wc = w & 3;          // 2 x 4 wave grid

  // chunked XCD swizzle: 1024 blocks, 8 XCDs, n-fastest within each chunk
  const int bx = blockIdx.x;
  const int swz = (bx & 7) * 128 + (bx >> 3);
  const int m0 = (swz >> 2) * 256;
  const int n0 = (swz & 3) * 256;

  // ---- A fragment base pointers (per-lane, fragment layout)
  const float* aPtr[8];
#pragma unroll
  for (int mi = 0; mi < 8; mi++)
    aPtr[mi] = X + (size_t)(m0 + wr * 128 + mi * 16 + (lane & 15)) * DIM
                 + (lane >> 4) * 8;

  // ---- B staging sources: 2 chunks/thread, sc = i*512 + tid (16B bf16 chunks)
  const unsigned short* bSrc[2];
#pragma unroll
  for (int i = 0; i < 2; i++) {
    int sc = i * 512 + tid;
    int srow = sc >> 3;
    int j = (sc & 7) ^ (srow & 7);
    int row = srow * 2 + (j >> 2);
    bSrc[i] = W1t + (size_t)(n0 + row) * DIM + (j & 3) * 8;
  }

  // ---- B fragment LDS byte offsets (within a 16KB buffer)
  int bOff[4];
#pragma unroll
  for (int ni = 0; ni < 4; ni++) {
    int row = wc * 64 + ni * 16 + (lane & 15);
    int srow = row >> 1;
    int ic = ((row & 1) * 4 + (lane >> 4)) ^ (srow & 7);
    bOff[ni] = srow * 128 + ic * 16;
  }

  f32x4 acc[8][4];
#pragma unroll
  for (int mi = 0; mi < 8; mi++)
#pragma unroll
    for (int ni = 0; ni < 4; ni++)
      acc[mi][ni] = (f32x4){0.f, 0.f, 0.f, 0.f};

  f32x4 aC[8][2];                             // single (depth-1) A register set
  short8 af[8], bfv[4];

#define LOAD_A(S) do {                                                  \
    _Pragma("unroll")                                                   \
    for (int mi = 0; mi < 8; mi++) {                                    \
      aC[mi][0] = *(const f32x4*)(aPtr[mi] + (S) * 32);                 \
      aC[mi][1] = *(const f32x4*)(aPtr[mi] + (S) * 32 + 4);             \
    }                                                                   \
  } while (0)

#define STAGE_B(S) do {                                                 \
    const int bufB_ = ((S) % 3) * 16384;                                \
    const int koF_ = (S) * 32;                                          \
    gload_lds16(bSrc[0] + koF_, lds + bufB_ + w * 1024);                \
    gload_lds16(bSrc[1] + koF_, lds + bufB_ + 8192 + w * 1024);         \
  } while (0)

#define KITER(S, PFA, PFB, VMSTR) do {                                  \
    asm volatile("s_waitcnt vmcnt(" VMSTR ")" ::: "memory");            \
    __builtin_amdgcn_s_barrier();                                       \
    __builtin_amdgcn_sched_barrier(0);                                  \
    _Pragma("unroll")                                                   \
    for (int mi = 0; mi < 8; mi++)                                      \
      af[mi] = cvt8(aC[mi][0], aC[mi][1]);                              \
    __builtin_amdgcn_sched_barrier(0);                                  \
    if (PFA) LOAD_A((S) + 1);                                           \
    if (PFB) STAGE_B((S) + 2);                                          \
    __builtin_amdgcn_sched_barrier(0);                                  \
    const char* bufB_ = lds + ((S) % 3) * 16384;                        \
    _Pragma("unroll")                                                   \
    for (int ni = 0; ni < 4; ni++)                                      \
      bfv[ni] = *(const short8*)(bufB_ + bOff[ni]);                     \
    __builtin_amdgcn_s_setprio(1);                                      \
    _Pragma("unroll")                                                   \
    for (int mi = 0; mi < 8; mi++)                                      \
      _Pragma("unroll")                                                 \
      for (int ni = 0; ni < 4; ni++)                                    \
        acc[mi][ni] = mfma_bf16(af[mi], bfv[ni], acc[mi][ni]);          \
    __builtin_amdgcn_s_setprio(0);                                      \
  } while (0)

  // prologue; VMEM queue (oldest->newest): B(0)[2], A(0)[16], B(1)[2]
  STAGE_B(0);
  LOAD_A(0);
  STAGE_B(1);

  for (int s = 0; s < 30; ++s) KITER(s, 1, 1, "2");
  KITER(30, 1, 0, "2");
  KITER(31, 0, 0, "0");

#undef KITER
#undef STAGE_B
#undef LOAD_A

  // epilogue: scores[row] += sum over this wave's 64 cols of tanh(c + b1) * w2
  const int cg = lane >> 4;   // row group: rows cg*4 + j
  const int cl = lane & 15;   // col within fragment
#pragma unroll
  for (int mi = 0; mi < 8; mi++) {
    float p0 = 0.f, p1 = 0.f, p2 = 0.f, p3 = 0.f;
#pragma unroll
    for (int ni = 0; ni < 4; ni++) {
      int col = n0 + wc * 64 + ni * 16 + cl;
      float w2v = w2[col];
      float b1v = b1[col];
      p0 += fast_tanh(acc[mi][ni][0] + b1v) * w2v;
      p1 += fast_tanh(acc[mi][ni][1] + b1v) * w2v;
      p2 += fast_tanh(acc[mi][ni][2] + b1v) * w2v;
      p3 += fast_tanh(acc[mi][ni][3] + b1v) * w2v;
    }
#pragma unroll
    for (int off = 1; off < 16; off <<= 1) {
      p0 += __shfl_xor(p0, off);
      p1 += __shfl_xor(p1, off);
      p2 += __shfl_xor(p2, off);
      p3 += __shfl_xor(p3, off);
    }
    if (cl == 0) {
      int row = m0 + wr * 128 + mi * 16 + cg * 4;
      atomicAdd(&scores[row + 0], p0);
      atomicAdd(&scores[row + 1], p1);
      atomicAdd(&scores[row + 2], p2);
      atomicAdd(&scores[row + 3], p3);
    }
  }
}

// ---------- kernel 3: masked softmax + u_att + u_last (fp32 X) ----------
__global__ __launch_bounds__(256) void attn_uatt_kernel(
    const float* __restrict__ X,
    const float* __restrict__ scores,
    const int* __restrict__ mask,
    float* __restrict__ u_att,
    float* __restrict__ u_last) {
  const int b = blockIdx.x;
  const int half = blockIdx.y;            // d-range [half*512, half*512+512)
  const int tid = threadIdx.x;
  const int lane = tid & 63;
  const int wave = tid >> 6;

  __shared__ float attn[SEQ];
  __shared__ float rbuf[4];
  __shared__ float part[3][64 * 9];       // padded stride 9

  float s0 = scores[(size_t)b * SEQ + tid];
  float s1 = scores[(size_t)b * SEQ + 256 + tid];
  if (mask[(size_t)b * SEQ + tid]) s0 = -1000000000.0f;
  if (mask[(size_t)b * SEQ + 256 + tid]) s1 = -1000000000.0f;

  float mx = fmaxf(s0, s1);
#pragma unroll
  for (int off = 1; off < 64; off <<= 1) mx = fmaxf(mx, __shfl_xor(mx, off));
  if (lane == 0) rbuf[wave] = mx;
  __syncthreads();
  mx = fmaxf(fmaxf(rbuf[0], rbuf[1]), fmaxf(rbuf[2], rbuf[3]));

  float p0 = expf(s0 - mx), p1 = expf(s1 - mx);
  float sm = p0 + p1;
#pragma unroll
  for (int off = 1; off < 64; off <<= 1) sm += __shfl_xor(sm, off);
  __syncthreads();
  if (lane == 0) rbuf[wave] = sm;
  __syncthreads();
  sm = rbuf[0] + rbuf[1] + rbuf[2] + rbuf[3];
  float inv = 1.0f / sm;
  attn[tid] = p0 * inv;
  attn[tid + 256] = p1 * inv;
  __syncthreads();

  // u_last: exact fp32 copy of X[:, 511, :] (this block's 512-d half)
  if (tid < 128) {
    ((f32x4*)u_last)[(size_t)b * 256 + half * 128 + tid] =
        ((const f32x4*)X)[((size_t)b * SEQ + (SEQ - 1)) * 256 + half * 128 + tid];
  }

  // u_att[b][d] = sum_s attn[s] * X[b][s][d]; block covers 512 d (64 groups of 8)
  const int col = tid & 63;            // 8-float group within the half
  const int sh = tid >> 6;             // s-range split: [sh*128, sh*128+128)
  const f32x4* Xp = (const f32x4*)X + (size_t)b * SEQ * 256 + half * 128 + col * 2;
  f32x4 a0 = {0.f, 0.f, 0.f, 0.f}, a1 = {0.f, 0.f, 0.f, 0.f};
  for (int s = sh * 128; s < sh * 128 + 128; s++) {
    float wgt = attn[s];
    a0 += wgt * Xp[(size_t)s * 256];
    a1 += wgt * Xp[(size_t)s * 256 + 1];
  }
  if (sh) {
#pragma unroll
    for (int j = 0; j < 4; j++) part[sh - 1][col * 9 + j] = a0[j];
#pragma unroll
    for (int j = 0; j < 4; j++) part[sh - 1][col * 9 + 4 + j] = a1[j];
  }
  __syncthreads();
  if (sh == 0) {
#pragma unroll
    for (int j = 0; j < 4; j++)
      a0[j] += part[0][col * 9 + j] + part[1][col * 9 + j] + part[2][col * 9 + j];
#pragma unroll
    for (int j = 0; j < 4; j++)
      a1[j] += part[0][col * 9 + 4 + j] + part[1][col * 9 + 4 + j] + part[2][col * 9 + 4 + j];
    f32x4* dst = (f32x4*)(u_att + (size_t)b * DIM + half * 512 + col * 8);
    dst[0] = a0;
    dst[1] = a1;
  }
}

// ---------- launcher ----------
extern "C" void kernel_launch(void* const* d_in, const int* in_sizes, int n_in,
                              void* d_out, int out_size, void* d_ws, size_t ws_size,
                              hipStream_t stream) {
  const float* X    = (const float*)d_in[0];   // [128][512][1024] fp32
  const int*   mask = (const int*)d_in[1];     // [128][512] int32 (bool)
  const float* W1   = (const float*)d_in[2];   // [1024][1024]
  const float* b1   = (const float*)d_in[3];   // [1024]
  const float* w2   = (const float*)d_in[4];   // [1024]

  float* out    = (float*)d_out;
  float* u_last = out;                          // [128][1024]
  float* u_att  = out + BATCH * DIM;            // [128][1024]

  char* ws = (char*)d_ws;
  unsigned short* W1t = (unsigned short*)ws;                        // 2 MB
  float* scores = (float*)(ws + (size_t)DIM * DIM * 2);             // 256 KB

  hipMemsetAsync(scores, 0, MROWS * sizeof(float), stream);
  hipLaunchKernelGGL(w1t_kernel, dim3(256), dim3(256), 0, stream, W1, W1t);
  hipLaunchKernelGGL(gemm_score_kernel, dim3(1024), dim3(512), 0, stream,
                     X, W1t, b1, w2, scores);
  hipLaunchKernelGGL(attn_uatt_kernel, dim3(128, 2), dim3(256), 0, stream,
                     X, scores, mask, u_att, u_last);
}

// Round 13
// 270.051 us; speedup vs baseline: 17.8854x; 2.5750x over previous
//
#include <hip/hip_runtime.h>
#include <hip/hip_bf16.h>
#include <cstdint>
#include <cstddef>

// Problem constants (fixed by the reference)
#define BATCH 128
#define SEQ   512
#define DIM   1024
#define MROWS (BATCH * SEQ)          // 65536
#define NT    32                     // K sub-tiles of 32 (DIM/32)

typedef short short8 __attribute__((ext_vector_type(8)));
typedef __bf16 bf16x8 __attribute__((ext_vector_type(8)));
typedef float f32x4 __attribute__((ext_vector_type(4)));

// ---------- MFMA wrapper: accept either builtin signature (short8 or bf16x8) ----------
template <typename VA> struct other_frag { using type = bf16x8; };
template <> struct other_frag<bf16x8> { using type = short8; };

template <typename VA>
__device__ __forceinline__ auto try_mfma(VA a, VA b, f32x4 c, int)
    -> decltype(__builtin_amdgcn_mfma_f32_16x16x32_bf16(a, b, c, 0, 0, 0)) {
  return __builtin_amdgcn_mfma_f32_16x16x32_bf16(a, b, c, 0, 0, 0);
}
template <typename VA>
__device__ __forceinline__ f32x4 try_mfma(VA a, VA b, f32x4 c, long) {
  using O = typename other_frag<VA>::type;
  O a2 = __builtin_bit_cast(O, a);
  O b2 = __builtin_bit_cast(O, b);
  return __builtin_amdgcn_mfma_f32_16x16x32_bf16(a2, b2, c, 0, 0, 0);
}
__device__ __forceinline__ f32x4 mfma_bf16(short8 a, short8 b, f32x4 c) {
  return try_mfma(a, b, c, 0);
}

// ---------- helpers ----------
__device__ __forceinline__ unsigned short f32_to_bf16(float f) {
  union { float f; uint32_t u; } v; v.f = f;
  uint32_t u = v.u;
  u += 0x7FFFu + ((u >> 16) & 1u);   // round-to-nearest-even
  return (unsigned short)(u >> 16);
}

// 8 x f32 -> 8 x bf16 (RNE); compiler lowers to v_cvt_pk_bf16_f32 pairs
__device__ __forceinline__ short8 cvt8(f32x4 a, f32x4 b) {
  bf16x8 o;
  o[0] = (__bf16)a[0]; o[1] = (__bf16)a[1]; o[2] = (__bf16)a[2]; o[3] = (__bf16)a[3];
  o[4] = (__bf16)b[0]; o[5] = (__bf16)b[1]; o[6] = (__bf16)b[2]; o[7] = (__bf16)b[3];
  return __builtin_bit_cast(short8, o);
}

__device__ __forceinline__ void gload_lds16(const void* g, void* l) {
  __builtin_amdgcn_global_load_lds(
      (__attribute__((address_space(1))) void*)g,
      (__attribute__((address_space(3))) void*)l,
      16, 0, 0);
}

__device__ __forceinline__ float fast_tanh(float x) {
  x = fminf(fmaxf(x, -15.0f), 15.0f);
  float e = __expf(2.0f * x);
  return (e - 1.0f) / (e + 1.0f);
}

// ---------- kernel 1: W1 (D x D) -> W1t bf16 (transposed, [e][d]) ----------
__global__ __launch_bounds__(256) void w1t_kernel(const float* __restrict__ W1,
                                                  unsigned short* __restrict__ W1t) {
  __shared__ float tile[64][65];
  int bx = blockIdx.x & 15;    // e-tile
  int by = blockIdx.x >> 4;    // d-tile
  int t = threadIdx.x;
  int c = t & 63, r0 = t >> 6;
#pragma unroll
  for (int i = 0; i < 16; i++) {
    int r = i * 4 + r0;
    tile[r][c] = W1[(size_t)(by * 64 + r) * DIM + bx * 64 + c];
  }
  __syncthreads();
#pragma unroll
  for (int i = 0; i < 16; i++) {
    int r = i * 4 + r0;
    W1t[(size_t)(bx * 64 + r) * DIM + by * 64 + c] = f32_to_bf16(tile[c][r]);
  }
}

// ---------- kernel 2: 256x256 GEMM, A reg-staged fp32 -> bf16 LDS ----------
// C[m][e] = sum_d bf16(X[m][d]) * W1t[e][d]; scores[m] += sum_e tanh(C+b1[e])*w2[e]
//
// R10 skeleton (counted vmcnt + one raw barrier per K32-subtile, XCD-chunked
// grid, measured-0 bank layouts) with A's LDS tile stored as BF16:
//   - R10 was LDS-read-bound: 160 KB ds_read/CU/subtile (fp32 A = 2x bytes,
//     cvt repeated per wc-wave).  bf16 A -> 96 KB reads + cvt once at staging.
//   - A staging: thread t loads 16 consecutive fp32 of row t>>1 (4 dwordx4;
//     16B pieces @64B stride across 32 rows/wave -- L2 absorbs), cvt8 x2,
//     2x ds_write_b128 into the verified granule scheme:
//       granule (srow = row>>1, j), j = j' ^ (srow&7), j' = (row&1)*4 + k8.
//     Write banks: per stride-8 lane group, 4 distinct j x 2 = 2-way (free).
//   - ds_write ordering: writes issue BEFORE this iter's ds_reads (pinned by
//     sched_barrier) -> in-order DS retirement means the compiler's lgkmcnt
//     wait for the reads also retires the writes before the wave reaches the
//     next barrier -> cross-wave visibility guaranteed.
//   - VMEM queue/thread (oldest->newest) at iter S entry:
//     [B(S)2 leftover, rA(S+1)4, B(S+1)2] -> vmcnt(2) retires B(S)+rA(S+1),
//     leaves B(S+1) in flight across the barrier.  Tail: iter 31 vmcnt(0).
//   - A ring-3 bf16 16KB + B ring-3 bf16 16KB = 96 KB LDS -> 1 block/CU; no
//     occupancy incentive for the allocator to squeeze VGPRs (R12 lesson).
// B path, fragment reads, epilogue: byte-identical to R10 (measured 0 confl).
__global__ __launch_bounds__(512, 2) void gemm_score_kernel(
    const float* __restrict__ X,              // [MROWS][DIM] fp32
    const unsigned short* __restrict__ W1t,   // [DIM][DIM]  (e-major)
    const float* __restrict__ b1,
    const float* __restrict__ w2,
    float* __restrict__ scores) {             // [MROWS]
  __shared__ __align__(16) char lds[98304];   // A: [0,48K)  B: [48K,96K)

  const int tid = threadIdx.x;
  const int lane = tid & 63;
  const int w = tid >> 6;                     // wave 0..7
  const int wr = w >> 2, wc = w & 3;          // 2 x 4 wave grid

  // chunked XCD swizzle: 1024 blocks, 8 XCDs, n-fastest within each chunk
  const int bx = blockIdx.x;
  const int swz = (bx & 7) * 128 + (bx >> 3);
  const int m0 = (swz >> 2) * 256;
  const int n0 = (swz & 3) * 256;

  // ---- A staging: thread t owns row = t>>1, floats (t&1)*16 .. +16
  const float* aSrcT = X + (size_t)(m0 + (tid >> 1)) * DIM + (tid & 1) * 16;
  // A LDS write offsets (2 granules, i = 0,1): srow = t>>2,
  // j' = ((t>>1)&1)*4 + (t&1)*2 + i, j = j' ^ (srow&7)
  int wOff[2];
  {
    int srow = tid >> 2;
    int j0 = ((tid >> 1) & 1) * 4 + (tid & 1) * 2;
#pragma unroll
    for (int i = 0; i < 2; i++)
      wOff[i] = srow * 128 + ((j0 + i) ^ (srow & 7)) * 16;
  }

  // ---- B staging sources: 2 chunks/thread, sc = i*512 + tid (16B bf16 chunks)
  const unsigned short* bSrc[2];
#pragma unroll
  for (int i = 0; i < 2; i++) {
    int sc = i * 512 + tid;
    int srow = sc >> 3;
    int j = (sc & 7) ^ (srow & 7);
    int row = srow * 2 + (j >> 2);
    bSrc[i] = W1t + (size_t)(n0 + row) * DIM + (j & 3) * 8;
  }

  // ---- fragment LDS byte offsets (identical scheme for A and B; measured 0)
  int aOff[8], bOff[4];
#pragma unroll
  for (int mi = 0; mi < 8; mi++) {
    int row = wr * 128 + mi * 16 + (lane & 15);
    int srow = row >> 1;
    int ic = ((row & 1) * 4 + (lane >> 4)) ^ (srow & 7);
    aOff[mi] = srow * 128 + ic * 16;
  }
#pragma unroll
  for (int ni = 0; ni < 4; ni++) {
    int row = wc * 64 + ni * 16 + (lane & 15);
    int srow = row >> 1;
    int ic = ((row & 1) * 4 + (lane >> 4)) ^ (srow & 7);
    bOff[ni] = srow * 128 + ic * 16;
  }

  f32x4 acc[8][4];
#pragma unroll
  for (int mi = 0; mi < 8; mi++)
#pragma unroll
    for (int ni = 0; ni < 4; ni++)
      acc[mi][ni] = (f32x4){0.f, 0.f, 0.f, 0.f};

  f32x4 rA0, rA1, rA2, rA3;                   // single A reg set (16 VGPR)
  short8 af[8], bfv[4];

#define LOAD_RA(S) do {                                                 \
    const float* p_ = aSrcT + (S) * 32;                                 \
    rA0 = *(const f32x4*)(p_);                                          \
    rA1 = *(const f32x4*)(p_ + 4);                                      \
    rA2 = *(const f32x4*)(p_ + 8);                                      \
    rA3 = *(const f32x4*)(p_ + 12);                                     \
  } while (0)

#define STAGE_B(S) do {                                                 \
    const int bufB_ = 49152 + ((S) % 3) * 16384;                        \
    const int koF_ = (S) * 32;                                          \
    gload_lds16(bSrc[0] + koF_, lds + bufB_ + w * 1024);                \
    gload_lds16(bSrc[1] + koF_, lds + bufB_ + 8192 + w * 1024);         \
  } while (0)

#define KITER(S, WR, PF, VMSTR) do {                                    \
    asm volatile("s_waitcnt vmcnt(" VMSTR ")" ::: "memory");            \
    __builtin_amdgcn_s_barrier();                                       \
    __builtin_amdgcn_sched_barrier(0);                                  \
    if (WR) {                                                           \
      char* aw_ = lds + (((S) + 1) % 3) * 16384;                        \
      *(short8*)(aw_ + wOff[0]) = cvt8(rA0, rA1);                       \
      *(short8*)(aw_ + wOff[1]) = cvt8(rA2, rA3);                       \
    }                                                                   \
    __builtin_amdgcn_sched_barrier(0);                                  \
    if (PF) {                                                           \
      LOAD_RA((S) + 2);                                                 \
      STAGE_B((S) + 2);                                                 \
    }                                                                   \
    const char* bufA_ = lds + ((S) % 3) * 16384;                        \
    const char* bufB_ = lds + 49152 + ((S) % 3) * 16384;                \
    _Pragma("unroll")                                                   \
    for (int mi = 0; mi < 8; mi++)                                      \
      af[mi] = *(const short8*)(bufA_ + aOff[mi]);                      \
    _Pragma("unroll")                                                   \
    for (int ni = 0; ni < 4; ni++)                                      \
      bfv[ni] = *(const short8*)(bufB_ + bOff[ni]);                     \
    __builtin_amdgcn_s_setprio(1);                                      \
    _Pragma("unroll")                                                   \
    for (int mi = 0; mi < 8; mi++)                                      \
      _Pragma("unroll")                                                 \
      for (int ni = 0; ni < 4; ni++)                                    \
        acc[mi][ni] = mfma_bf16(af[mi], bfv[ni], acc[mi][ni]);          \
    __builtin_amdgcn_s_setprio(0);                                      \
  } while (0)

  // prologue: A(0) -> regs -> LDS slot 0; then queue [rA(1)4, B(0)2, B(1)2]
  LOAD_RA(0);
  asm volatile("s_waitcnt vmcnt(0)" ::: "memory");
  {
    char* aw = lds;                           // slot 0
    *(short8*)(aw + wOff[0]) = cvt8(rA0, rA1);
    *(short8*)(aw + wOff[1]) = cvt8(rA2, rA3);
  }
  LOAD_RA(1);
  STAGE_B(0);
  STAGE_B(1);
  asm volatile("s_waitcnt lgkmcnt(0)" ::: "memory");  // A(0) writes drained

  for (int s = 0; s < 30; ++s) KITER(s, 1, 1, "2");
  KITER(30, 1, 0, "2");
  KITER(31, 0, 0, "0");

#undef KITER
#undef STAGE_B
#undef LOAD_RA

  // epilogue: scores[row] += sum over this wave's 64 cols of tanh(c + b1) * w2
  const int cg = lane >> 4;   // row group: rows cg*4 + j
  const int cl = lane & 15;   // col within fragment
#pragma unroll
  for (int mi = 0; mi < 8; mi++) {
    float p0 = 0.f, p1 = 0.f, p2 = 0.f, p3 = 0.f;
#pragma unroll
    for (int ni = 0; ni < 4; ni++) {
      int col = n0 + wc * 64 + ni * 16 + cl;
      float w2v = w2[col];
      float b1v = b1[col];
      p0 += fast_tanh(acc[mi][ni][0] + b1v) * w2v;
      p1 += fast_tanh(acc[mi][ni][1] + b1v) * w2v;
      p2 += fast_tanh(acc[mi][ni][2] + b1v) * w2v;
      p3 += fast_tanh(acc[mi][ni][3] + b1v) * w2v;
    }
#pragma unroll
    for (int off = 1; off < 16; off <<= 1) {
      p0 += __shfl_xor(p0, off);
      p1 += __shfl_xor(p1, off);
      p2 += __shfl_xor(p2, off);
      p3 += __shfl_xor(p3, off);
    }
    if (cl == 0) {
      int row = m0 + wr * 128 + mi * 16 + cg * 4;
      atomicAdd(&scores[row + 0], p0);
      atomicAdd(&scores[row + 1], p1);
      atomicAdd(&scores[row + 2], p2);
      atomicAdd(&scores[row + 3], p3);
    }
  }
}

// ---------- kernel 3: masked softmax + u_att + u_last (fp32 X) ----------
__global__ __launch_bounds__(256) void attn_uatt_kernel(
    const float* __restrict__ X,
    const float* __restrict__ scores,
    const int* __restrict__ mask,
    float* __restrict__ u_att,
    float* __restrict__ u_last) {
  const int b = blockIdx.x;
  const int half = blockIdx.y;            // d-range [half*512, half*512+512)
  const int tid = threadIdx.x;
  const int lane = tid & 63;
  const int wave = tid >> 6;

  __shared__ float attn[SEQ];
  __shared__ float rbuf[4];
  __shared__ float part[3][64 * 9];       // padded stride 9

  float s0 = scores[(size_t)b * SEQ + tid];
  float s1 = scores[(size_t)b * SEQ + 256 + tid];
  if (mask[(size_t)b * SEQ + tid]) s0 = -1000000000.0f;
  if (mask[(size_t)b * SEQ + 256 + tid]) s1 = -1000000000.0f;

  float mx = fmaxf(s0, s1);
#pragma unroll
  for (int off = 1; off < 64; off <<= 1) mx = fmaxf(mx, __shfl_xor(mx, off));
  if (lane == 0) rbuf[wave] = mx;
  __syncthreads();
  mx = fmaxf(fmaxf(rbuf[0], rbuf[1]), fmaxf(rbuf[2], rbuf[3]));

  float p0 = expf(s0 - mx), p1 = expf(s1 - mx);
  float sm = p0 + p1;
#pragma unroll
  for (int off = 1; off < 64; off <<= 1) sm += __shfl_xor(sm, off);
  __syncthreads();
  if (lane == 0) rbuf[wave] = sm;
  __syncthreads();
  sm = rbuf[0] + rbuf[1] + rbuf[2] + rbuf[3];
  float inv = 1.0f / sm;
  attn[tid] = p0 * inv;
  attn[tid + 256] = p1 * inv;
  __syncthreads();

  // u_last: exact fp32 copy of X[:, 511, :] (this block's 512-d half)
  if (tid < 128) {
    ((f32x4*)u_last)[(size_t)b * 256 + half * 128 + tid] =
        ((const f32x4*)X)[((size_t)b * SEQ + (SEQ - 1)) * 256 + half * 128 + tid];
  }

  // u_att[b][d] = sum_s attn[s] * X[b][s][d]; block covers 512 d (64 groups of 8)
  const int col = tid & 63;            // 8-float group within the half
  const int sh = tid >> 6;             // s-range split: [sh*128, sh*128+128)
  const f32x4* Xp = (const f32x4*)X + (size_t)b * SEQ * 256 + half * 128 + col * 2;
  f32x4 a0 = {0.f, 0.f, 0.f, 0.f}, a1 = {0.f, 0.f, 0.f, 0.f};
  for (int s = sh * 128; s < sh * 128 + 128; s++) {
    float wgt = attn[s];
    a0 += wgt * Xp[(size_t)s * 256];
    a1 += wgt * Xp[(size_t)s * 256 + 1];
  }
  if (sh) {
#pragma unroll
    for (int j = 0; j < 4; j++) part[sh - 1][col * 9 + j] = a0[j];
#pragma unroll
    for (int j = 0; j < 4; j++) part[sh - 1][col * 9 + 4 + j] = a1[j];
  }
  __syncthreads();
  if (sh == 0) {
#pragma unroll
    for (int j = 0; j < 4; j++)
      a0[j] += part[0][col * 9 + j] + part[1][col * 9 + j] + part[2][col * 9 + j];
#pragma unroll
    for (int j = 0; j < 4; j++)
      a1[j] += part[0][col * 9 + 4 + j] + part[1][col * 9 + 4 + j] + part[2][col * 9 + 4 + j];
    f32x4* dst = (f32x4*)(u_att + (size_t)b * DIM + half * 512 + col * 8);
    dst[0] = a0;
    dst[1] = a1;
  }
}

// ---------- launcher ----------
extern "C" void kernel_launch(void* const* d_in, const int* in_sizes, int n_in,
                              void* d_out, int out_size, void* d_ws, size_t ws_size,
                              hipStream_t stream) {
  const float* X    = (const float*)d_in[0];   // [128][512][1024] fp32
  const int*   mask = (const int*)d_in[1];     // [128][512] int32 (bool)
  const float* W1   = (const float*)d_in[2];   // [1024][1024]
  const float* b1   = (const float*)d_in[3];   // [1024]
  const float* w2   = (const float*)d_in[4];   // [1024]

  float* out    = (float*)d_out;
  float* u_last = out;                          // [128][1024]
  float* u_att  = out + BATCH * DIM;            // [128][1024]

  char* ws = (char*)d_ws;
  unsigned short* W1t = (unsigned short*)ws;                        // 2 MB
  float* scores = (float*)(ws + (size_t)DIM * DIM * 2);             // 256 KB

  hipMemsetAsync(scores, 0, MROWS * sizeof(float), stream);
  hipLaunchKernelGGL(w1t_kernel, dim3(256), dim3(256), 0, stream, W1, W1t);
  hipLaunchKernelGGL(gemm_score_kernel, dim3(1024), dim3(512), 0, stream,
                     X, W1t, b1, w2, scores);
  hipLaunchKernelGGL(attn_uatt_kernel, dim3(128, 2), dim3(256), 0, stream,
                     X, scores, mask, u_att, u_last);
}

// Round 14
// 225.183 us; speedup vs baseline: 21.4490x; 1.1992x over previous
//
#include <hip/hip_runtime.h>
#include <hip/hip_bf16.h>
#include <cstdint>
#include <cstddef>

// Problem constants (fixed by the reference)
#define BATCH 128
#define SEQ   512
#define DIM   1024
#define MROWS (BATCH * SEQ)          // 65536
#define NT    32                     // K sub-tiles of 32 (DIM/32)

typedef short short8 __attribute__((ext_vector_type(8)));
typedef __bf16 bf16x8 __attribute__((ext_vector_type(8)));
typedef float f32x4 __attribute__((ext_vector_type(4)));

// ---------- MFMA wrapper: accept either builtin signature (short8 or bf16x8) ----------
template <typename VA> struct other_frag { using type = bf16x8; };
template <> struct other_frag<bf16x8> { using type = short8; };

template <typename VA>
__device__ __forceinline__ auto try_mfma(VA a, VA b, f32x4 c, int)
    -> decltype(__builtin_amdgcn_mfma_f32_16x16x32_bf16(a, b, c, 0, 0, 0)) {
  return __builtin_amdgcn_mfma_f32_16x16x32_bf16(a, b, c, 0, 0, 0);
}
template <typename VA>
__device__ __forceinline__ f32x4 try_mfma(VA a, VA b, f32x4 c, long) {
  using O = typename other_frag<VA>::type;
  O a2 = __builtin_bit_cast(O, a);
  O b2 = __builtin_bit_cast(O, b);
  return __builtin_amdgcn_mfma_f32_16x16x32_bf16(a2, b2, c, 0, 0, 0);
}
__device__ __forceinline__ f32x4 mfma_bf16(short8 a, short8 b, f32x4 c) {
  return try_mfma(a, b, c, 0);
}

// ---------- helpers ----------
__device__ __forceinline__ unsigned short f32_to_bf16(float f) {
  union { float f; uint32_t u; } v; v.f = f;
  uint32_t u = v.u;
  u += 0x7FFFu + ((u >> 16) & 1u);   // round-to-nearest-even
  return (unsigned short)(u >> 16);
}

// 8 x f32 -> 8 x bf16 (RNE)
__device__ __forceinline__ short8 cvt8(f32x4 a, f32x4 b) {
  bf16x8 o;
  o[0] = (__bf16)a[0]; o[1] = (__bf16)a[1]; o[2] = (__bf16)a[2]; o[3] = (__bf16)a[3];
  o[4] = (__bf16)b[0]; o[5] = (__bf16)b[1]; o[6] = (__bf16)b[2]; o[7] = (__bf16)b[3];
  return __builtin_bit_cast(short8, o);
}

__device__ __forceinline__ void gload_lds16(const void* g, void* l) {
  __builtin_amdgcn_global_load_lds(
      (__attribute__((address_space(1))) void*)g,
      (__attribute__((address_space(3))) void*)l,
      16, 0, 0);
}

__device__ __forceinline__ float fast_tanh(float x) {
  x = fminf(fmaxf(x, -15.0f), 15.0f);
  float e = __expf(2.0f * x);
  return (e - 1.0f) / (e + 1.0f);
}

// ---------- kernel 1: W1 (D x D) -> W1t bf16 (transposed, [e][d]) ----------
__global__ __launch_bounds__(256) void w1t_kernel(const float* __restrict__ W1,
                                                  unsigned short* __restrict__ W1t) {
  __shared__ float tile[64][65];
  int bx = blockIdx.x & 15;    // e-tile
  int by = blockIdx.x >> 4;    // d-tile
  int t = threadIdx.x;
  int c = t & 63, r0 = t >> 6;
#pragma unroll
  for (int i = 0; i < 16; i++) {
    int r = i * 4 + r0;
    tile[r][c] = W1[(size_t)(by * 64 + r) * DIM + bx * 64 + c];
  }
  __syncthreads();
#pragma unroll
  for (int i = 0; i < 16; i++) {
    int r = i * 4 + r0;
    W1t[(size_t)(bx * 64 + r) * DIM + by * 64 + c] = f32_to_bf16(tile[c][r]);
  }
}

// ---------- kernel 2: 256x256-tile pipelined GEMM (fp32 A direct) ----------
// C[m][e] = sum_d bf16(X[m][d]) * W1t[e][d]; scores[m] += sum_e tanh(C+b1[e])*w2[e]
//
// R10 kernel (best: 250 us total, 0 bank conflicts) with ONE parameter change:
// wave grid 2Mx4N -> 4Mx2N (wave tile 128x64 -> 64x128).  Rationale: R10 is
// LDS-read-bound (160 KB ds_read/CU/subtile); 4Mx2N halves A-read duplication
// (A frag rows read by 2 waves instead of 4): per-wave reads 16 fp32-A + 4
// bf16-B -> 8 fp32-A + 8 bf16-B = 128 KB/CU/subtile (-20% on the binding
// resource), and consume-side cvt_pk halves.  Bank-safety preserved: frag row
// bases shift by multiples of 16 rows, so both measured-0 XOR schemes keep 8
// distinct granule-columns per stride-8 lane group (R10-validated HW model).
//
// Everything else identical to R10:
//   A fp32 [256 rows][32 k]: 128-B stored row, granule js = q ^ (row&7) ^
//     ((row>>3)&7); ring-3 x 32 KB.  4 gloads/thread/subtile.
//   B bf16 row-pairs in 128-B stored rows, js = ((row&1)*4+k16) ^ (srow&7);
//     ring-3 x 16 KB.  2 gloads/thread/subtile.
//   One raw barrier + counted vmcnt(6) per subtile (tail 0); XCD-chunked grid.
__global__ __launch_bounds__(512, 2) void gemm_score_kernel(
    const float* __restrict__ X,              // [MROWS][DIM] fp32
    const unsigned short* __restrict__ W1t,   // [DIM][DIM]  (e-major)
    const float* __restrict__ b1,
    const float* __restrict__ w2,
    float* __restrict__ scores) {             // [MROWS]
  __shared__ __align__(16) char lds[147456];  // A: [0,96K)  B: [96K,144K)

  const int tid = threadIdx.x;
  const int lane = tid & 63;
  const int w = tid >> 6;                     // wave 0..7
  const int wr = w >> 1, wc = w & 1;          // 4 x 2 wave grid, 64x128 each

  // chunked XCD swizzle: 1024 blocks, 8 XCDs, n-fastest within each chunk
  const int bx = blockIdx.x;
  const int swz = (bx & 7) * 128 + (bx >> 3);
  const int m0 = (swz >> 2) * 256;
  const int n0 = (swz & 3) * 256;

  // ---- A staging sources: 4 chunks/thread, sc = i*512 + tid.
  // row = sc>>3, js = sc&7, q = js ^ (row&7) ^ ((row>>3)&7).
  const float* aSrc[4];
#pragma unroll
  for (int i = 0; i < 4; i++) {
    int sc = i * 512 + tid;
    int row = sc >> 3;
    int q = (sc & 7) ^ (row & 7) ^ ((row >> 3) & 7);
    aSrc[i] = X + (size_t)(m0 + row) * DIM + q * 4;
  }
  // ---- B staging sources: 2 chunks/thread, sc = i*512 + tid (16B bf16 chunks)
  const unsigned short* bSrc[2];
#pragma unroll
  for (int i = 0; i < 2; i++) {
    int sc = i * 512 + tid;
    int srow = sc >> 3;
    int j = (sc & 7) ^ (srow & 7);
    int row = srow * 2 + (j >> 2);
    bSrc[i] = W1t + (size_t)(n0 + row) * DIM + (j & 3) * 8;
  }

  // ---- fragment LDS byte offsets
  // A: within a 32KB fp32 buffer; [mi][c], c = low/high f32x4 of the 8 floats
  int aOff[4][2];
#pragma unroll
  for (int mi = 0; mi < 4; mi++) {
    int row = wr * 64 + mi * 16 + (lane & 15);
    int m = (row & 7) ^ ((row >> 3) & 7);
#pragma unroll
    for (int c = 0; c < 2; c++) {
      int js = ((lane >> 4) * 2 + c) ^ m;
      aOff[mi][c] = row * 128 + js * 16;
    }
  }
  int bOff[8];                                // B: within a 16KB bf16 buffer
#pragma unroll
  for (int ni = 0; ni < 8; ni++) {
    int row = wc * 128 + ni * 16 + (lane & 15);
    int srow = row >> 1;
    int ic = ((row & 1) * 4 + (lane >> 4)) ^ (srow & 7);
    bOff[ni] = srow * 128 + ic * 16;
  }

  f32x4 acc[4][8];
#pragma unroll
  for (int mi = 0; mi < 4; mi++)
#pragma unroll
    for (int ni = 0; ni < 8; ni++)
      acc[mi][ni] = (f32x4){0.f, 0.f, 0.f, 0.f};

  short8 af[4], bfv[8];

#define STAGE(S) do {                                                   \
    const int bufA_ = ((S) % 3) * 32768;                                \
    const int bufB_ = 98304 + ((S) % 3) * 16384;                        \
    const int koF_ = (S) * 32;                                          \
    gload_lds16(aSrc[0] + koF_, lds + bufA_ + w * 1024);                \
    gload_lds16(aSrc[1] + koF_, lds + bufA_ + 8192 + w * 1024);         \
    gload_lds16(aSrc[2] + koF_, lds + bufA_ + 16384 + w * 1024);        \
    gload_lds16(aSrc[3] + koF_, lds + bufA_ + 24576 + w * 1024);        \
    gload_lds16(bSrc[0] + koF_, lds + bufB_ + w * 1024);                \
    gload_lds16(bSrc[1] + koF_, lds + bufB_ + 8192 + w * 1024);         \
  } while (0)

#define KITER(S, VMSTR) do {                                            \
    asm volatile("s_waitcnt vmcnt(" VMSTR ")" ::: "memory");            \
    __builtin_amdgcn_s_barrier();                                       \
    __builtin_amdgcn_sched_barrier(0);                                  \
    if ((S) + 2 < NT) STAGE((S) + 2);                                   \
    const char* bufA_ = lds + ((S) % 3) * 32768;                        \
    const char* bufB_ = lds + 98304 + ((S) % 3) * 16384;                \
    _Pragma("unroll")                                                   \
    for (int mi = 0; mi < 4; mi++) {                                    \
      f32x4 lo_ = *(const f32x4*)(bufA_ + aOff[mi][0]);                 \
      f32x4 hi_ = *(const f32x4*)(bufA_ + aOff[mi][1]);                 \
      af[mi] = cvt8(lo_, hi_);                                          \
    }                                                                   \
    _Pragma("unroll")                                                   \
    for (int ni = 0; ni < 8; ni++)                                      \
      bfv[ni] = *(const short8*)(bufB_ + bOff[ni]);                     \
    __builtin_amdgcn_s_setprio(1);                                      \
    _Pragma("unroll")                                                   \
    for (int mi = 0; mi < 4; mi++)                                      \
      _Pragma("unroll")                                                 \
      for (int ni = 0; ni < 8; ni++)                                    \
        acc[mi][ni] = mfma_bf16(af[mi], bfv[ni], acc[mi][ni]);          \
    __builtin_amdgcn_s_setprio(0);                                      \
  } while (0)

  // prologue: 2 sub-tiles in flight (12 wave-loads)
  STAGE(0); STAGE(1);

  for (int s = 0; s < NT - 1; ++s) KITER(s, "6");
  KITER(NT - 1, "0");

#undef STAGE
#undef KITER

  // epilogue: scores[row] += sum over this wave's 128 cols of tanh(c + b1) * w2
  const int cg = lane >> 4;   // row group: rows cg*4 + j
  const int cl = lane & 15;   // col within fragment
#pragma unroll
  for (int mi = 0; mi < 4; mi++) {
    float p0 = 0.f, p1 = 0.f, p2 = 0.f, p3 = 0.f;
#pragma unroll
    for (int ni = 0; ni < 8; ni++) {
      int col = n0 + wc * 128 + ni * 16 + cl;
      float w2v = w2[col];
      float b1v = b1[col];
      p0 += fast_tanh(acc[mi][ni][0] + b1v) * w2v;
      p1 += fast_tanh(acc[mi][ni][1] + b1v) * w2v;
      p2 += fast_tanh(acc[mi][ni][2] + b1v) * w2v;
      p3 += fast_tanh(acc[mi][ni][3] + b1v) * w2v;
    }
#pragma unroll
    for (int off = 1; off < 16; off <<= 1) {
      p0 += __shfl_xor(p0, off);
      p1 += __shfl_xor(p1, off);
      p2 += __shfl_xor(p2, off);
      p3 += __shfl_xor(p3, off);
    }
    if (cl == 0) {
      int row = m0 + wr * 64 + mi * 16 + cg * 4;
      atomicAdd(&scores[row + 0], p0);
      atomicAdd(&scores[row + 1], p1);
      atomicAdd(&scores[row + 2], p2);
      atomicAdd(&scores[row + 3], p3);
    }
  }
}

// ---------- kernel 3: masked softmax + u_att + u_last (fp32 X) ----------
__global__ __launch_bounds__(256) void attn_uatt_kernel(
    const float* __restrict__ X,
    const float* __restrict__ scores,
    const int* __restrict__ mask,
    float* __restrict__ u_att,
    float* __restrict__ u_last) {
  const int b = blockIdx.x;
  const int half = blockIdx.y;            // d-range [half*512, half*512+512)
  const int tid = threadIdx.x;
  const int lane = tid & 63;
  const int wave = tid >> 6;

  __shared__ float attn[SEQ];
  __shared__ float rbuf[4];
  __shared__ float part[3][64 * 9];       // padded stride 9

  float s0 = scores[(size_t)b * SEQ + tid];
  float s1 = scores[(size_t)b * SEQ + 256 + tid];
  if (mask[(size_t)b * SEQ + tid]) s0 = -1000000000.0f;
  if (mask[(size_t)b * SEQ + 256 + tid]) s1 = -1000000000.0f;

  float mx = fmaxf(s0, s1);
#pragma unroll
  for (int off = 1; off < 64; off <<= 1) mx = fmaxf(mx, __shfl_xor(mx, off));
  if (lane == 0) rbuf[wave] = mx;
  __syncthreads();
  mx = fmaxf(fmaxf(rbuf[0], rbuf[1]), fmaxf(rbuf[2], rbuf[3]));

  float p0 = expf(s0 - mx), p1 = expf(s1 - mx);
  float sm = p0 + p1;
#pragma unroll
  for (int off = 1; off < 64; off <<= 1) sm += __shfl_xor(sm, off);
  __syncthreads();
  if (lane == 0) rbuf[wave] = sm;
  __syncthreads();
  sm = rbuf[0] + rbuf[1] + rbuf[2] + rbuf[3];
  float inv = 1.0f / sm;
  attn[tid] = p0 * inv;
  attn[tid + 256] = p1 * inv;
  __syncthreads();

  // u_last: exact fp32 copy of X[:, 511, :] (this block's 512-d half)
  if (tid < 128) {
    ((f32x4*)u_last)[(size_t)b * 256 + half * 128 + tid] =
        ((const f32x4*)X)[((size_t)b * SEQ + (SEQ - 1)) * 256 + half * 128 + tid];
  }

  // u_att[b][d] = sum_s attn[s] * X[b][s][d]; block covers 512 d (64 groups of 8)
  const int col = tid & 63;            // 8-float group within the half
  const int sh = tid >> 6;             // s-range split: [sh*128, sh*128+128)
  const f32x4* Xp = (const f32x4*)X + (size_t)b * SEQ * 256 + half * 128 + col * 2;
  f32x4 a0 = {0.f, 0.f, 0.f, 0.f}, a1 = {0.f, 0.f, 0.f, 0.f};
  for (int s = sh * 128; s < sh * 128 + 128; s++) {
    float wgt = attn[s];
    a0 += wgt * Xp[(size_t)s * 256];
    a1 += wgt * Xp[(size_t)s * 256 + 1];
  }
  if (sh) {
#pragma unroll
    for (int j = 0; j < 4; j++) part[sh - 1][col * 9 + j] = a0[j];
#pragma unroll
    for (int j = 0; j < 4; j++) part[sh - 1][col * 9 + 4 + j] = a1[j];
  }
  __syncthreads();
  if (sh == 0) {
#pragma unroll
    for (int j = 0; j < 4; j++)
      a0[j] += part[0][col * 9 + j] + part[1][col * 9 + j] + part[2][col * 9 + j];
#pragma unroll
    for (int j = 0; j < 4; j++)
      a1[j] += part[0][col * 9 + 4 + j] + part[1][col * 9 + 4 + j] + part[2][col * 9 + 4 + j];
    f32x4* dst = (f32x4*)(u_att + (size_t)b * DIM + half * 512 + col * 8);
    dst[0] = a0;
    dst[1] = a1;
  }
}

// ---------- launcher ----------
extern "C" void kernel_launch(void* const* d_in, const int* in_sizes, int n_in,
                              void* d_out, int out_size, void* d_ws, size_t ws_size,
                              hipStream_t stream) {
  const float* X    = (const float*)d_in[0];   // [128][512][1024] fp32
  const int*   mask = (const int*)d_in[1];     // [128][512] int32 (bool)
  const float* W1   = (const float*)d_in[2];   // [1024][1024]
  const float* b1   = (const float*)d_in[3];   // [1024]
  const float* w2   = (const float*)d_in[4];   // [1024]

  float* out    = (float*)d_out;
  float* u_last = out;                          // [128][1024]
  float* u_att  = out + BATCH * DIM;            // [128][1024]

  char* ws = (char*)d_ws;
  unsigned short* W1t = (unsigned short*)ws;                        // 2 MB
  float* scores = (float*)(ws + (size_t)DIM * DIM * 2);             // 256 KB

  hipMemsetAsync(scores, 0, MROWS * sizeof(float), stream);
  hipLaunchKernelGGL(w1t_kernel, dim3(256), dim3(256), 0, stream, W1, W1t);
  hipLaunchKernelGGL(gemm_score_kernel, dim3(1024), dim3(512), 0, stream,
                     X, W1t, b1, w2, scores);
  hipLaunchKernelGGL(attn_uatt_kernel, dim3(128, 2), dim3(256), 0, stream,
                     X, scores, mask, u_att, u_last);
}